// Round 8
// baseline (122.901 us; speedup 1.0000x reference)
//
#include <hip/hip_runtime.h>
#include <math.h>

// PRNN J2 plane-strain elastoplasticity scan.
// B=16384, T=128, F=3, MATPTS=16 (P=262144), O=3.
// R8: R7 layout (2 packed points/thread, 8 lanes/batch, 32 batches/block,
// 2 waves/SIMD) with the cross-lane reduction SOFTWARE-PIPELINED one
// 4-step block behind the physics, using schedulable builtin DPP adds
// (no asm barrier). No step's critical path contains a cross-lane op.

#define BLOCK 256
#define BPB 32              // batch elements per block (8 lanes each)
#define TSTEPS 128
#define ROWF (TSTEPS * 3)   // 384 floats per batch row
#define ROWP 388            // padded stride: 16B-aligned

typedef float v2 __attribute__((ext_vector_type(2)));

static __device__ __forceinline__ v2 vfma(v2 a, v2 b, v2 c) {
    return __builtin_elementwise_fma(a, b, c);
}
static __device__ __forceinline__ v2 vmax(v2 a, v2 b) {
    return __builtin_elementwise_max(a, b);
}

// one fused-able DPP add stage: v += dpp_mov(v, ctrl) with 0-fill.
// ctrl must be a literal => macro. GCNDPPCombine fuses to v_add_f32_dpp.
#define DPP_ADDST(v, ctrl)                                                   \
    v += __int_as_float(__builtin_amdgcn_update_dpp(                         \
        0, __float_as_int(v), (ctrl), 0xf, 0xf, true))

// 8-lane butterfly sum: quad_perm xor1 (0xB1), quad_perm xor2 (0x4E),
// row_half_mirror (0x141). All 8 lanes end with the group sum.
#define RED8(v)                                                              \
    do { DPP_ADDST(v, 0xB1); DPP_ADDST(v, 0x4E); DPP_ADDST(v, 0x141); } while (0)

__global__ __launch_bounds__(BLOCK, 2)
void prnn_j2_kernel(const float* __restrict__ x,
                    const float* __restrict__ W1,
                    const float* __restrict__ W2,
                    float* __restrict__ out)
{
    constexpr float MU    = (float)(3130.0 / (2.0 * (1.0 + 0.37)));
    constexpr float LAM   = (float)(3130.0 * 0.37 / ((1.0 + 0.37) * (1.0 - 2.0 * 0.37)));
    constexpr float SIG_Y = 64.8f;
    constexpr float H_ISO = 300.0f;
    const float TWO_MU  = 2.0f * MU;
    const float INV_DEN = 1.0f / (3.0f * MU + H_ISO);
    const float K3P     = (3.0f * MU) * INV_DEN;   // k = K3P * f * rq
    const float HP      = H_ISO * INV_DEN;         // yld += HP * f
    const float KBULK   = LAM + TWO_MU * (1.0f / 3.0f);
    const float C_Q2    = 6.0f * MU * MU;

    // +12 floats: harmless one-block-over prefetch on the last iteration
    __shared__ float xs[BPB * ROWP + 12];

    const int tid = threadIdx.x;
    const int g   = tid >> 3;       // local batch 0..31
    const int l   = tid & 7;        // lane in 8-group; points (l, l+8)
    const int blockBase = blockIdx.x * (BPB * ROWF);

    // ---- stage x into LDS (coalesced float4 global reads) ----
    {
        const float4* xg = (const float4*)(x + blockBase);
        for (int i4 = tid; i4 < BPB * ROWF / 4; i4 += BLOCK) {
            int b  = i4 / (ROWF / 4);
            int r4 = i4 - b * (ROWF / 4);
            ((float4*)(xs + b * ROWP))[r4] = xg[i4];
        }
    }

    // ---- packed per-thread weights: .x = point l, .y = point l+8 ----
    const int pa = l, pb = l + 8;
    v2 w1p[3][3], w2p[3][3];
    #pragma unroll
    for (int c = 0; c < 3; ++c)
        #pragma unroll
        for (int f = 0; f < 3; ++f) {
            w1p[c][f].x = W1[(3 * pa + c) * 3 + f];
            w1p[c][f].y = W1[(3 * pb + c) * 3 + f];
        }
    #pragma unroll
    for (int o = 0; o < 3; ++o)
        #pragma unroll
        for (int c = 0; c < 3; ++c) {
            float wa = W2[o * 48 + 3 * pa + c];
            float wb = W2[o * 48 + 3 * pb + c];
            w2p[o][c].x = fmaxf(wa, 0.0f) + log1pf(expf(-fabsf(wa)));
            w2p[o][c].y = fmaxf(wb, 0.0f) + log1pf(expf(-fabsf(wb)));
        }

    __syncthreads();

    v2 p0 = {0.f,0.f}, p1 = {0.f,0.f}, p2 = {0.f,0.f}, p3 = {0.f,0.f};
    v2 yld = {SIG_Y, SIG_Y};
    float* xrow = &xs[g * ROWP];
    const float4* xv = (const float4*)xrow;   // g*1552 B, 16B aligned
    const bool wact = (l < 3);

#define J2_PHYS(x0_, x1_, x2_, o0_, o1_, o2_)                                \
  {                                                                          \
    const float x0s = (x0_), x1s = (x1_), x2s = (x2_);                       \
    const v2 x0 = {x0s, x0s}, x1 = {x1s, x1s}, x2 = {x2s, x2s};              \
    const v2 e0 = vfma(w1p[0][0], x0, vfma(w1p[0][1], x1, w1p[0][2] * x2));  \
    const v2 e1 = vfma(w1p[1][0], x0, vfma(w1p[1][1], x1, w1p[1][2] * x2));  \
    const v2 e2 = vfma(w1p[2][0], x0, vfma(w1p[2][1], x1, w1p[2][2] * x2));  \
    const v2 ee_xx = e0 - p0;                                                \
    const v2 ee_yy = e1 - p1;                                                \
    const v2 ee_xy = 0.5f * e2 - p3;                                         \
    const v2 tr = (ee_xx + ee_yy) - p2;                                      \
    const v2 c3 = tr * (1.0f / 3.0f);                                        \
    const v2 exd = ee_xx - c3;                                               \
    const v2 eyd = ee_yy - c3;                                               \
    const v2 ezd = -p2 - c3;                                                 \
    v2 u = exd * exd;                                                        \
    u = vfma(eyd, eyd, u);                                                   \
    u = vfma(ezd, ezd, u);                                                   \
    u = vfma(ee_xy * ee_xy, (v2){2.0f, 2.0f}, u);                            \
    const v2 q2 = vmax(C_Q2 * u, (v2){1e-24f, 1e-24f});                      \
    v2 rq;                                                                   \
    rq.x = __builtin_amdgcn_rsqf(q2.x);                                      \
    rq.y = __builtin_amdgcn_rsqf(q2.y);                                      \
    const v2 q = q2 * rq;                                                    \
    const v2 f = vmax(q - yld, (v2){0.0f, 0.0f});                            \
    yld = vfma((v2){HP, HP}, f, yld);                                        \
    const v2 k   = (K3P * f) * rq;                                           \
    const v2 omk = 1.0f - k;                                                 \
    const v2 pm  = KBULK * tr;                                               \
    const v2 s0 = vfma(TWO_MU * exd, omk, pm);                               \
    const v2 s1 = vfma(TWO_MU * eyd, omk, pm);                               \
    const v2 s2 = (TWO_MU * ee_xy) * omk;                                    \
    p0 = vfma(k, exd, p0);                                                   \
    p1 = vfma(k, eyd, p1);                                                   \
    p2 = vfma(k, ezd, p2);                                                   \
    p3 = vfma(k, ee_xy, p3);                                                 \
    v2 r0 = vfma(w2p[0][0], s0, vfma(w2p[0][1], s1, w2p[0][2] * s2));        \
    v2 r1 = vfma(w2p[1][0], s0, vfma(w2p[1][1], s1, w2p[1][2] * s2));        \
    v2 r2 = vfma(w2p[2][0], s0, vfma(w2p[2][1], s1, w2p[2][2] * s2));        \
    o0_ = r0.x + r0.y;                                                       \
    o1_ = r1.x + r1.y;                                                       \
    o2_ = r2.x + r2.y;                                                       \
  }

// physics for a 4-step block held in A0..A2, outputs into 12 scalars
#define PHYS_BLOCK(r)                                                        \
    J2_PHYS(A0.x, A0.y, A0.z, r[0],  r[1],  r[2]);                           \
    J2_PHYS(A0.w, A1.x, A1.y, r[3],  r[4],  r[5]);                           \
    J2_PHYS(A1.z, A1.w, A2.x, r[6],  r[7],  r[8]);                           \
    J2_PHYS(A2.y, A2.z, A2.w, r[9],  r[10], r[11])

// reduce 12 partials (schedulable DPP) and write block 'bi''s outputs
#define RED_WRITE(r, bi)                                                     \
  {                                                                          \
    _Pragma("unroll")                                                        \
    for (int i = 0; i < 12; ++i) { RED8(r[i]); }                             \
    if (wact) {                                                              \
        float* wp = xrow + 12 * (bi) + l;                                    \
        wp[0] = (l == 0) ? r[0] : ((l == 1) ? r[1]  : r[2]);                 \
        wp[3] = (l == 0) ? r[3] : ((l == 1) ? r[4]  : r[5]);                 \
        wp[6] = (l == 0) ? r[6] : ((l == 1) ? r[7]  : r[8]);                 \
        wp[9] = (l == 0) ? r[9] : ((l == 1) ? r[10] : r[11]);                \
    }                                                                        \
  }

    float4 A0 = xv[0], A1 = xv[1], A2 = xv[2];
    float rprev[12];

    // prologue: physics for block 0, reduction deferred
    {
        float4 An0 = xv[3], An1 = xv[4], An2 = xv[5];
        PHYS_BLOCK(rprev);
        A0 = An0; A1 = An1; A2 = An2;
    }

    for (int tb = 1; tb < TSTEPS / 4; ++tb) {
        // prefetch block tb+1 (last iter over-reads into pad)
        float4 An0 = xv[3 * tb + 3];
        float4 An1 = xv[3 * tb + 4];
        float4 An2 = xv[3 * tb + 5];

        float rcur[12];
        PHYS_BLOCK(rcur);          // block tb physics (independent of rprev)
        RED_WRITE(rprev, tb - 1);  // block tb-1 reduction — overlaps physics

        #pragma unroll
        for (int i = 0; i < 12; ++i) rprev[i] = rcur[i];
        A0 = An0; A1 = An1; A2 = An2;
    }

    // epilogue: reduce+write the final block
    RED_WRITE(rprev, TSTEPS / 4 - 1);

#undef PHYS_BLOCK
#undef RED_WRITE
#undef J2_PHYS

    __syncthreads();

    // ---- coalesced float4 flush LDS -> out ----
    {
        float4* og = (float4*)(out + blockBase);
        for (int i4 = tid; i4 < BPB * ROWF / 4; i4 += BLOCK) {
            int b  = i4 / (ROWF / 4);
            int r4 = i4 - b * (ROWF / 4);
            og[i4] = ((const float4*)(xs + b * ROWP))[r4];
        }
    }
}

extern "C" void kernel_launch(void* const* d_in, const int* in_sizes, int n_in,
                              void* d_out, int out_size, void* d_ws, size_t ws_size,
                              hipStream_t stream) {
    const float* x  = (const float*)d_in[0];
    const float* W1 = (const float*)d_in[1];
    const float* W2 = (const float*)d_in[2];
    float* out = (float*)d_out;

    const int B = 16384;
    dim3 grid(B / BPB);   // 512 blocks
    dim3 block(BLOCK);
    prnn_j2_kernel<<<grid, block, 0, stream>>>(x, W1, W2, out);
}